// Round 1
// baseline (636.670 us; speedup 1.0000x reference)
//
#include <hip/hip_runtime.h>

// numpy never contracts mul+add: products are rounded then added. File-wide.
// The sgemm dot uses __builtin_fmaf explicitly (OpenBLAS vfmadd231ps).
#pragma clang fp contract(off)

#define NN 512
#define DD 256

typedef int int4v __attribute__((ext_vector_type(4)));

// ---------------------------------------------------------------------------
// numpy f32 pairwise-sum leaf, n=128, AVX512 path (verified bit-exact R11):
// 16 lane-partials over stride-16 elements, vector tree
// ((q0+q1)+(q2+q3))+((q4+q5)+(q6+q7)), then reduce_add lane-halving.
// ---------------------------------------------------------------------------
__device__ __forceinline__ float np_leaf128(const float* __restrict__ x)
{
    float p[16];
    #pragma unroll
    for (int i = 0; i < 16; ++i) {
        const float q0 = x[i]       * x[i];
        const float q1 = x[i + 16]  * x[i + 16];
        const float q2 = x[i + 32]  * x[i + 32];
        const float q3 = x[i + 48]  * x[i + 48];
        const float q4 = x[i + 64]  * x[i + 64];
        const float q5 = x[i + 80]  * x[i + 80];
        const float q6 = x[i + 96]  * x[i + 96];
        const float q7 = x[i + 112] * x[i + 112];
        p[i] = ((q0 + q1) + (q2 + q3)) + ((q4 + q5) + (q6 + q7));
    }
    float q[8];
    #pragma unroll
    for (int i = 0; i < 8; ++i) q[i] = p[i] + p[i + 8];
    const float s0 = q[0] + q[4];
    const float s1 = q[1] + q[5];
    const float s2 = q[2] + q[6];
    const float s3 = q[3] + q[7];
    return (s0 + s2) + (s1 + s3);
}

// ---------------------------------------------------------------------------
// Fused TripletMarginMiner — R11 numerics exactly, with TWO store-path
// changes aimed at the write-BW gap vs fillBuffer (6.2 TB/s):
//   1. Stores are PLAIN dwordx4 (NT flag removed). Full-line coalesced
//      stores never RFO; NT's evict-first policy buys nothing and may
//      defeat TCC write-combining (fill hits 6.2 TB/s with plain stores).
//   2. Each anchor's p-range is split across 2 blocks (grid 1024, 512 thr)
//      -> 32 waves/CU (full occupancy) and halved per-block prologue
//      serialization ahead of the store stream. Prologue (sq/dot) is
//      recomputed per block: +256 MB of L2-resident reads ~= 7 us agg.
//
//   sq   : np.sum(emb*emb,axis=1) — AVX512 pairwise leaves (above).
//   dot  : OpenBLAS sgemm — single f32 accumulator, sequential k, FMA.
//   mat  : fl32(fl32(sq_a+sq_j) - fl32(2*dot)), relu.
//   mask : sames(a,p)&(p!=a)&diffs(a,n)&(fl32(mat_an-mat_ap) <= 0.2f)
//          validity folded: dn=+inf (diff fails), mp=NaN (same fails).
// Block (a,seg): anchor a, p in [seg*256, seg*256+256). 512 threads;
// coalesced int4 stores, n fastest.
// ---------------------------------------------------------------------------
__global__ __launch_bounds__(512)
void triplet_kernel(const float* __restrict__ emb,
                    const int* __restrict__ lab,
                    int* __restrict__ out)
{
    __shared__ int   canon[NN];
    __shared__ float arow[DD];
    __shared__ float dn[NN];
    __shared__ float mp[NN];
    __shared__ float sq_a_sh;
    __shared__ int   det_lab64;

    const int a   = blockIdx.x >> 1;   // anchor
    const int seg = blockIdx.x & 1;    // p-range half
    const int t   = threadIdx.x;       // 0..511

    // labels width canonicalization (values in [0,32): int64 staging has all
    // 256 odd int32 words zero; genuine int32 fails that w.p. 1-32^-256)
    if (t == 0) det_lab64 = 0;
    __syncthreads();
    if (t < 256 && lab[2 * t + 1] == 0) atomicAdd(&det_lab64, 1);
    __syncthreads();
    canon[t] = (det_lab64 == 256) ? lab[2 * t] : lab[t];

    if (t < DD) arow[t] = emb[(size_t)a * DD + t];
    __syncthreads();

    // ---- sq_j (numpy SIMD pairwise) ----
    const float* __restrict__ xr = emb + (size_t)t * DD;
    const float sqj = np_leaf128(xr) + np_leaf128(xr + 128);
    if (t == a) sq_a_sh = sqj;

    // ---- dot(a,j): sequential-k single-accumulator FMA (sgemm kernel) ----
    float dot = 0.0f;
    for (int k = 0; k < DD; ++k)
        dot = __builtin_fmaf(arow[k], xr[k], dot);
    __syncthreads();   // sq_a_sh visible

    // ---- mat[a][t], f32, numpy op tree ----
    const float t1 = sq_a_sh + sqj;
    const float t2 = 2.0f * dot;       // exact scale
    float m = t1 - t2;
    m = m > 0.0f ? m : 0.0f;

    const int la = canon[a];
    dn[t] = (canon[t] != la) ? m : __builtin_inff();
    mp[t] = (canon[t] == la && t != a) ? m : __builtin_nanf("");
    __syncthreads();

    // ---- write this block's 256x512 int32 slab: PLAIN coalesced int4 ----
    const int tx = t & 127;      // 4 consecutive n per thread
    const int ty = t >> 7;       // 0..3 strides p
    const float d0 = dn[4 * tx + 0];
    const float d1 = dn[4 * tx + 1];
    const float d2 = dn[4 * tx + 2];
    const float d3 = dn[4 * tx + 3];

    int4v* base = (int4v*)out + (size_t)a * NN * (NN / 4) + tx;
    const int p_end = seg * (NN / 2) + (NN / 2);
    #pragma unroll 4
    for (int p = seg * (NN / 2) + ty; p < p_end; p += 4) {
        const float mpp = mp[p];             // LDS broadcast
        int4v r;
        r.x = ((d0 - mpp) <= 0.2f) ? 1 : 0;  // inf/NaN fold validity to 0
        r.y = ((d1 - mpp) <= 0.2f) ? 1 : 0;
        r.z = ((d2 - mpp) <= 0.2f) ? 1 : 0;
        r.w = ((d3 - mpp) <= 0.2f) ? 1 : 0;
        base[(size_t)p * (NN / 4)] = r;      // plain dwordx4 store
    }
}

// ---------------------------------------------------------------------------
extern "C" void kernel_launch(void* const* d_in, const int* in_sizes, int n_in,
                              void* d_out, int out_size, void* d_ws, size_t ws_size,
                              hipStream_t stream)
{
    const float* emb    = (const float*)d_in[0];
    const int*   labels = (const int*)d_in[1];
    int*         out    = (int*)d_out;
    (void)d_ws; (void)ws_size;   // deliberately unused: ws use costs ~+30us

    triplet_kernel<<<2 * NN, 512, 0, stream>>>(emb, labels, out);
}

// Round 2
// 614.235 us; speedup vs baseline: 1.0365x; 1.0365x over previous
//
#include <hip/hip_runtime.h>

// numpy never contracts mul+add: products are rounded then added. File-wide.
// The sgemm dot uses __builtin_fmaf explicitly (OpenBLAS vfmadd231ps).
#pragma clang fp contract(off)

#define NN 512
#define DD 256

typedef int   int4v   __attribute__((ext_vector_type(4)));
typedef float float4v __attribute__((ext_vector_type(4)));

// ---------------------------------------------------------------------------
// Fused single-pass row kernel: computes BOTH
//   sq  = numpy f32 pairwise-sum of x*x, n=256 = leaf128(x) + leaf128(x+128)
//         (AVX512 tree, verified bit-exact R11: 16 lane-partials over
//          stride-16, tree ((q0+q1)+(q2+q3))+((q4+q5)+(q6+q7)), then
//          q[i]=p[i]+p[i+8], s-pair halving)
//   dot = OpenBLAS sgemm single-accumulator sequential-k FMA vs arow
// in ONE float4 pass over the row (64 dwordx4 instead of ~512 scalar loads,
// and the row is read once instead of twice). The pairwise tree is built
// with a staged A/B/P state machine whose ops are bit-identical to the
// two-pass version; the dot chain order (k ascending) is unchanged.
// All loops fully unrolled -> compile-time indices -> registers (rule #20).
// ---------------------------------------------------------------------------
__device__ __forceinline__ void row_pass(const float* __restrict__ x,
                                         const float* __restrict__ ar,
                                         float& sq_out, float& dot_out)
{
    float dot = 0.0f;
    float leafsum0 = 0.0f, leafsum1 = 0.0f;
    #pragma unroll
    for (int l = 0; l < 2; ++l) {
        const float* __restrict__ xl = x + 128 * l;
        const float* __restrict__ al = ar + 128 * l;
        float A[16], B[16], P[16];
        #pragma unroll
        for (int q = 0; q < 8; ++q) {
            #pragma unroll
            for (int i0 = 0; i0 < 16; i0 += 4) {
                const int o = 16 * q + i0;
                const float4v v  = *(const float4v*)(xl + o);
                const float4v a4 = *(const float4v*)(al + o);
                // dot chain: sequential k = 128*l + o + {0,1,2,3}
                dot = __builtin_fmaf(a4.x, v.x, dot);
                dot = __builtin_fmaf(a4.y, v.y, dot);
                dot = __builtin_fmaf(a4.z, v.z, dot);
                dot = __builtin_fmaf(a4.w, v.w, dot);
                // pairwise-tree staging (exact associativity of np_leaf128)
                #pragma unroll
                for (int j = 0; j < 4; ++j) {
                    const int i = i0 + j;
                    const float xx = (j == 0) ? v.x : (j == 1) ? v.y
                                   : (j == 2) ? v.z : v.w;
                    const float qq = xx * xx;
                    if      (q == 0) A[i] = qq;
                    else if (q == 1) A[i] = A[i] + qq;               // q0+q1
                    else if (q == 2) B[i] = qq;
                    else if (q == 3) { B[i] = B[i] + qq;             // q2+q3
                                       P[i] = A[i] + B[i]; }         // (..)+(..)
                    else if (q == 4) A[i] = qq;
                    else if (q == 5) A[i] = A[i] + qq;               // q4+q5
                    else if (q == 6) B[i] = qq;
                    else             { B[i] = B[i] + qq;             // q6+q7
                                       P[i] = P[i] + (A[i] + B[i]); }
                }
            }
        }
        float qr[8];
        #pragma unroll
        for (int i = 0; i < 8; ++i) qr[i] = P[i] + P[i + 8];
        const float s0 = qr[0] + qr[4];
        const float s1 = qr[1] + qr[5];
        const float s2 = qr[2] + qr[6];
        const float s3 = qr[3] + qr[7];
        const float leaf = (s0 + s2) + (s1 + s3);
        if (l == 0) leafsum0 = leaf; else leafsum1 = leaf;
    }
    sq_out  = leafsum0 + leafsum1;
    dot_out = dot;
}

// ---------------------------------------------------------------------------
// Fused TripletMarginMiner — R12 store path EXACTLY (best: NT stores, one
// block per anchor, 512 threads; plain stores cost +35us, seg-split costs
// +35us — both measured and rejected). ONE change vs R12: the prologue's
// row reads are single-pass float4 (row_pass above) instead of two passes
// of per-lane scalar loads (~8x less TA address-divergence pressure).
//
//   mat  : fl32(fl32(sq_a+sq_j) - fl32(2*dot)), relu.
//   mask : sames(a,p)&(p!=a)&diffs(a,n)&(fl32(mat_an-mat_ap) <= 0.2f)
//          validity folded: dn=+inf (diff fails), mp=NaN (same fails).
// Coalesced int4 NT stores, n fastest.
// ---------------------------------------------------------------------------
__global__ __launch_bounds__(512)
void triplet_kernel(const float* __restrict__ emb,
                    const int* __restrict__ lab,
                    int* __restrict__ out)
{
    __shared__ int   canon[NN];
    __shared__ float arow[DD];
    __shared__ float dn[NN];
    __shared__ float mp[NN];
    __shared__ float sq_a_sh;
    __shared__ int   det_lab64;

    const int a = blockIdx.x;
    const int t = threadIdx.x;   // 0..511

    // labels width canonicalization (values in [0,32): int64 staging has all
    // 256 odd int32 words zero; genuine int32 fails that w.p. 1-32^-256)
    if (t == 0) det_lab64 = 0;
    __syncthreads();
    if (t < 256 && lab[2 * t + 1] == 0) atomicAdd(&det_lab64, 1);
    __syncthreads();
    canon[t] = (det_lab64 == 256) ? lab[2 * t] : lab[t];

    if (t < DD) arow[t] = emb[(size_t)a * DD + t];
    __syncthreads();

    // ---- sq_j + dot(a,j): single fused float4 pass ----
    const float* __restrict__ xr = emb + (size_t)t * DD;
    float sqj, dot;
    row_pass(xr, arow, sqj, dot);
    if (t == a) sq_a_sh = sqj;
    __syncthreads();   // sq_a_sh visible

    // ---- mat[a][t], f32, numpy op tree ----
    const float t1 = sq_a_sh + sqj;
    const float t2 = 2.0f * dot;       // exact scale
    float m = t1 - t2;
    m = m > 0.0f ? m : 0.0f;

    const int la = canon[a];
    dn[t] = (canon[t] != la) ? m : __builtin_inff();
    mp[t] = (canon[t] == la && t != a) ? m : __builtin_nanf("");
    __syncthreads();

    // ---- write the 512x512 int32 slab: NONTEMPORAL coalesced int4 ----
    const int tx = t & 127;      // 4 consecutive n per thread
    const int ty = t >> 7;       // 0..3 strides p
    const float d0 = dn[4 * tx + 0];
    const float d1 = dn[4 * tx + 1];
    const float d2 = dn[4 * tx + 2];
    const float d3 = dn[4 * tx + 3];

    int4v* base = (int4v*)out + (size_t)a * NN * (NN / 4) + tx;
    for (int p = ty; p < NN; p += 4) {
        const float mpp = mp[p];             // LDS broadcast
        int4v r;
        r.x = ((d0 - mpp) <= 0.2f) ? 1 : 0;  // inf/NaN fold validity to 0
        r.y = ((d1 - mpp) <= 0.2f) ? 1 : 0;
        r.z = ((d2 - mpp) <= 0.2f) ? 1 : 0;
        r.w = ((d3 - mpp) <= 0.2f) ? 1 : 0;
        __builtin_nontemporal_store(r, base + (size_t)p * (NN / 4));
    }
}

// ---------------------------------------------------------------------------
extern "C" void kernel_launch(void* const* d_in, const int* in_sizes, int n_in,
                              void* d_out, int out_size, void* d_ws, size_t ws_size,
                              hipStream_t stream)
{
    const float* emb    = (const float*)d_in[0];
    const int*   labels = (const int*)d_in[1];
    int*         out    = (int*)d_out;
    (void)d_ws; (void)ws_size;   // deliberately unused: ws use costs ~+30us

    triplet_kernel<<<NN, 512, 0, stream>>>(emb, labels, out);
}

// Round 3
// 566.802 us; speedup vs baseline: 1.1233x; 1.0837x over previous
//
#include <hip/hip_runtime.h>

// numpy never contracts mul+add: products are rounded then added. File-wide.
// The sgemm dot uses __builtin_fmaf explicitly (OpenBLAS vfmadd231ps).
#pragma clang fp contract(off)

#define NN 512
#define DD 256

typedef int   int4v   __attribute__((ext_vector_type(4)));
typedef float float4v __attribute__((ext_vector_type(4)));

// ---------------------------------------------------------------------------
// Fused single-pass row kernel (arithmetic VERIFIED bit-exact in R2, absmax 0):
//   sq  = numpy f32 pairwise leaf128(x)+leaf128(x+128), AVX512 tree
//         ((q0+q1)+(q2+q3))+((q4+q5)+(q6+q7)) via staged A/B/P state machine
//   dot = OpenBLAS sgemm single-accumulator sequential-k FMA
// R2's regression was CODEGEN, not math: full 64-load unroll + 48 live tree
// floats -> load hoisting -> VGPR >128 -> occupancy drop + spills (+47us).
// R3 fixes codegen only:
//   - anchor row read via WAVE-UNIFORM global pointer with compile-time
//     indices -> compiler emits scalar s_load; SGPR operand feeds v_fma
//     directly (1 sgpr/VALU ok). Deletes 256 ds_read_b32/thread AND the
//     arow LDS staging.
//   - sched_barrier(0) per 16-elem stage: max 4 float4 loads in flight,
//     VGPR ~80-90, keeps 4 waves/SIMD (512-thr block, 2 blocks/CU).
// ---------------------------------------------------------------------------
__device__ __forceinline__ void row_pass(const float* __restrict__ x,
                                         const float* __restrict__ ar,  // uniform
                                         float& sq_out, float& dot_out)
{
    float dot = 0.0f;
    float leaf0 = 0.0f, leaf1 = 0.0f;
    #pragma unroll
    for (int l = 0; l < 2; ++l) {
        const float* __restrict__ xl = x + 128 * l;
        const float* __restrict__ al = ar + 128 * l;
        float A[16], B[16], P[16];
        #pragma unroll
        for (int q = 0; q < 8; ++q) {
            #pragma unroll
            for (int i0 = 0; i0 < 16; i0 += 4) {
                const int o = 16 * q + i0;
                const float4v v = *(const float4v*)(xl + o);
                // dot chain: sequential k = 128*l + o + {0,1,2,3};
                // al[o+j] is wave-uniform -> s_load -> SGPR src of v_fma
                dot = __builtin_fmaf(al[o + 0], v.x, dot);
                dot = __builtin_fmaf(al[o + 1], v.y, dot);
                dot = __builtin_fmaf(al[o + 2], v.z, dot);
                dot = __builtin_fmaf(al[o + 3], v.w, dot);
                // pairwise-tree staging (exact associativity of np_leaf128)
                #pragma unroll
                for (int j = 0; j < 4; ++j) {
                    const int i = i0 + j;
                    const float xx = (j == 0) ? v.x : (j == 1) ? v.y
                                   : (j == 2) ? v.z : v.w;
                    const float qq = xx * xx;
                    if      (q == 0) A[i] = qq;
                    else if (q == 1) A[i] = A[i] + qq;               // q0+q1
                    else if (q == 2) B[i] = qq;
                    else if (q == 3) { B[i] = B[i] + qq;             // q2+q3
                                       P[i] = A[i] + B[i]; }
                    else if (q == 4) A[i] = qq;
                    else if (q == 5) A[i] = A[i] + qq;               // q4+q5
                    else if (q == 6) B[i] = qq;
                    else             { B[i] = B[i] + qq;             // q6+q7
                                       P[i] = P[i] + (A[i] + B[i]); }
                }
            }
            // cap scheduler load-hoisting: bounds VGPR, preserves occupancy
            __builtin_amdgcn_sched_barrier(0);
        }
        float qr[8];
        #pragma unroll
        for (int i = 0; i < 8; ++i) qr[i] = P[i] + P[i + 8];
        const float s0 = qr[0] + qr[4];
        const float s1 = qr[1] + qr[5];
        const float s2 = qr[2] + qr[6];
        const float s3 = qr[3] + qr[7];
        const float leaf = (s0 + s2) + (s1 + s3);
        if (l == 0) leaf0 = leaf; else leaf1 = leaf;
    }
    sq_out  = leaf0 + leaf1;
    dot_out = dot;
}

// ---------------------------------------------------------------------------
// Fused TripletMarginMiner — R0 store path EXACTLY (best measured: NT stores,
// one block per anchor, 512 threads; plain stores +35us, seg-split +35us,
// both measured and rejected). Prologue: codegen-controlled fused row pass.
//
//   mat  : fl32(fl32(sq_a+sq_j) - fl32(2*dot)), relu.
//   mask : sames(a,p)&(p!=a)&diffs(a,n)&(fl32(mat_an-mat_ap) <= 0.2f)
//          validity folded: dn=+inf (diff fails), mp=NaN (same fails).
// Coalesced int4 NT stores, n fastest.
// ---------------------------------------------------------------------------
__global__ __launch_bounds__(512)
void triplet_kernel(const float* __restrict__ emb,
                    const int* __restrict__ lab,
                    int* __restrict__ out)
{
    __shared__ int   canon[NN];
    __shared__ float dn[NN];
    __shared__ float mp[NN];
    __shared__ float sq_a_sh;
    __shared__ int   det_lab64;

    const int a = blockIdx.x;
    const int t = threadIdx.x;   // 0..511

    // labels width canonicalization (values in [0,32): int64 staging has all
    // 256 odd int32 words zero; genuine int32 fails that w.p. 1-32^-256)
    if (t == 0) det_lab64 = 0;
    __syncthreads();
    if (t < 256 && lab[2 * t + 1] == 0) atomicAdd(&det_lab64, 1);
    __syncthreads();
    canon[t] = (det_lab64 == 256) ? lab[2 * t] : lab[t];

    // ---- sq_j + dot(a,j): single fused float4 pass, anchor row scalar ----
    const float* __restrict__ xr    = emb + (size_t)t * DD;
    const float* __restrict__ aptr  = emb + (size_t)a * DD;   // wave-uniform
    float sqj, dot;
    row_pass(xr, aptr, sqj, dot);
    if (t == a) sq_a_sh = sqj;
    __syncthreads();   // sq_a_sh AND canon[] visible

    // ---- mat[a][t], f32, numpy op tree ----
    const float t1 = sq_a_sh + sqj;
    const float t2 = 2.0f * dot;       // exact scale
    float m = t1 - t2;
    m = m > 0.0f ? m : 0.0f;

    const int la = canon[a];
    dn[t] = (canon[t] != la) ? m : __builtin_inff();
    mp[t] = (canon[t] == la && t != a) ? m : __builtin_nanf("");
    __syncthreads();

    // ---- write the 512x512 int32 slab: NONTEMPORAL coalesced int4 ----
    const int tx = t & 127;      // 4 consecutive n per thread
    const int ty = t >> 7;       // 0..3 strides p
    const float d0 = dn[4 * tx + 0];
    const float d1 = dn[4 * tx + 1];
    const float d2 = dn[4 * tx + 2];
    const float d3 = dn[4 * tx + 3];

    int4v* base = (int4v*)out + (size_t)a * NN * (NN / 4) + tx;
    for (int p = ty; p < NN; p += 4) {
        const float mpp = mp[p];             // LDS broadcast
        int4v r;
        r.x = ((d0 - mpp) <= 0.2f) ? 1 : 0;  // inf/NaN fold validity to 0
        r.y = ((d1 - mpp) <= 0.2f) ? 1 : 0;
        r.z = ((d2 - mpp) <= 0.2f) ? 1 : 0;
        r.w = ((d3 - mpp) <= 0.2f) ? 1 : 0;
        __builtin_nontemporal_store(r, base + (size_t)p * (NN / 4));
    }
}

// ---------------------------------------------------------------------------
extern "C" void kernel_launch(void* const* d_in, const int* in_sizes, int n_in,
                              void* d_out, int out_size, void* d_ws, size_t ws_size,
                              hipStream_t stream)
{
    const float* emb    = (const float*)d_in[0];
    const int*   labels = (const int*)d_in[1];
    int*         out    = (int*)d_out;
    (void)d_ws; (void)ws_size;   // deliberately unused: ws use costs ~+30us

    triplet_kernel<<<NN, 512, 0, stream>>>(emb, labels, out);
}